// Round 1
// 1016.742 us; speedup vs baseline: 1.0489x; 1.0489x over previous
//
#include <hip/hip_runtime.h>
#include <hip/hip_fp16.h>

// S=2048, B=32, H=1024.
// out[b][s] = softmax_s( sum_h tanh( (enc[s][b] @ We)[h] + hproj[b][h] ) * v[h] )
//
// GEMM: M = 65536 rows (K-contiguous), K = 2048, N = 1024.
// Block = 512 threads (8 waves) owns a 64-row M-slab and ALL of N:
//   wave w computes nt=w (128 cols), acc 4(m) x 8(n) frags.
// A (enc f32) is read from HBM exactly once; B (packed fp16 We, 4 MB) is
// L2-resident and re-read per block.
//
// PIPELINE (this revision): B is staged per-wave (glds into the wave's own
// LDS region, read only by that wave) -> B needs NO barrier, only a counted
// per-wave vmcnt. A (4 KB tile, cross-wave) is staged global->reg early,
// cvt+ds_write LATE (after MFMA), synced with raw s_barrier + lgkmcnt(0)
// only. No vmcnt(0) drain anywhere in the steady-state loop:
//   iter t: [issue A(t+1) ld] [issue 8 glds B(t+1)] [vmcnt(9): B(t) ready]
//           [ds_read + 32 MFMA on tile t] [vmcnt(8) auto: A(t+1) ready]
//           [cvt+ds_write A(t+1)] [lgkmcnt(0); s_barrier]
// kt unrolled by 2 with DISTINCT __shared__ objects so AA can prove the
// glds destination never aliases the ds_read source buffer.

typedef _Float16 half8 __attribute__((ext_vector_type(8)));
typedef float floatx4 __attribute__((ext_vector_type(4)));
typedef float f32x4 __attribute__((ext_vector_type(4)));

constexpr int SEQ = 2048;
constexpr int BAT = 32;
constexpr int HID = 1024;
constexpr int KDIM = 2048;
constexpr int MTOT = SEQ * BAT;   // 65536
constexpr int KT = 64;            // K tiles of 32

constexpr int B_BUF = 65536;          // 8 nt * 512 chunks * 16B
constexpr int A_PITCH = 64 * 16 + 16; // 1040 B per fg group (pad breaks bank alias)
constexpr int A_BUF = 4 * A_PITCH;    // 4160

__device__ __forceinline__ void glds16(const void* g, void* l) {
    __builtin_amdgcn_global_load_lds((__attribute__((address_space(1))) void*)(g),
                                     (__attribute__((address_space(3))) void*)(l), 16, 0, 0);
}

// ---------------------------------------------------------------------------
// Pack We into fp16 chunks: packB[((nt*64+kt)*512 + fg*128 + n)*8 + j]
//   = We[kt*32 + fg*8 + j][nt*128 + n]
// ---------------------------------------------------------------------------
__global__ __launch_bounds__(256) void pack_b_kernel(const float* __restrict__ W,
                                                     _Float16* __restrict__ pb) {
    int t = blockIdx.x * blockDim.x + threadIdx.x;   // 0..262143
    int nt = t >> 15;
    int rem = t & 32767;
    int kt = rem >> 9;
    int c = rem & 511;
    int g = c >> 7;
    int n = c & 127;
    int h = nt * 128 + n;
    int e0 = kt * 32 + g * 8;
    const float* src = W + (size_t)(1024 + e0) * 1024 + h;
    union { _Float16 hh[8]; uint4 u; } tmp;
#pragma unroll
    for (int j = 0; j < 8; ++j) tmp.hh[j] = (_Float16)src[(size_t)j * 1024];
    *(uint4*)(pb + (size_t)t * 8) = tmp.u;
}

// ---------------------------------------------------------------------------
// hproj[b][h] = hidden[b] . W[:,h] + bias[h]. 4-way K-split, 512 blocks.
// ---------------------------------------------------------------------------
__global__ __launch_bounds__(256) void hproj_kernel(const float* __restrict__ hidden,
                                                    const float* __restrict__ W,
                                                    const float* __restrict__ bias,
                                                    float* __restrict__ hp) {
    int b = blockIdx.x;                 // 0..31
    int h0 = blockIdx.y * 64;           // 16 y-blocks
    int hl = threadIdx.x & 63;
    int ks = threadIdx.x >> 6;          // 0..3
    const float* hr = hidden + b * HID + ks * 256;
    const float* wc = W + (size_t)(ks * 256) * HID + h0 + hl;
    float acc = 0.0f;
#pragma unroll 8
    for (int e = 0; e < 256; ++e) acc += hr[e] * wc[(size_t)e * HID];
    __shared__ float red[256];
    red[threadIdx.x] = acc;
    __syncthreads();
    if (threadIdx.x < 64)
        hp[b * HID + h0 + threadIdx.x] = red[threadIdx.x] + red[64 + threadIdx.x] +
                                         red[128 + threadIdx.x] + red[192 + threadIdx.x] +
                                         bias[h0 + threadIdx.x];
}

// ---------------------------------------------------------------------------
// Main fused kernel.
// ---------------------------------------------------------------------------
__global__ __launch_bounds__(512, 2) void attn_gemm_kernel(
    const float* __restrict__ enc, const _Float16* __restrict__ pb,
    const float* __restrict__ hp, const float* __restrict__ v,
    float* __restrict__ score) {
    // Distinct objects (not one big array): lets alias analysis prove the
    // glds DMA destination buffer != the ds_read source buffer, so the
    // waitcnt pass does not insert serializing vmcnt(0) before frag reads.
    __shared__ char sB0v[B_BUF];
    __shared__ char sB1v[B_BUF];
    __shared__ char sA0v[A_BUF];
    __shared__ char sA1v[A_BUF];

    const int tid = threadIdx.x;
    const int lane = tid & 63;
    const int wv = tid >> 6;            // 0..7 == nt
    const int mt = blockIdx.x;          // 0..1023
    const size_t r0 = (size_t)mt * 64;
    const int fm = lane & 15;
    const int fg = lane >> 4;

    // B staging: wave wv stages nt=wv. 8 glds16 per thread per kt.
    const char* bg = (const char*)pb + (size_t)wv * KT * 8192;
    const int bl_off = wv * 8192;

    // A staging: thread loads one float4 of the 64x32 f32 tile per kt.
    const int arow = tid >> 3;          // 0..63
    const int ac4 = tid & 7;            // float4 col
    const f32x4* agp = (const f32x4*)(enc + (r0 + arow) * KDIM) + ac4;
    const int awoff = (ac4 >> 1) * A_PITCH + arow * 16 + (ac4 & 1) * 8;

    // Fragment read offsets.
    const int ardoff = fg * A_PITCH + fm * 16;
    const int brdoff = wv * 8192 + fg * 2048 + fm * 16;

    floatx4 acc[4][8];
#pragma unroll
    for (int i = 0; i < 4; ++i)
#pragma unroll
        for (int j = 0; j < 8; ++j) acc[i][j] = (floatx4)0.0f;

    // ---- prologue: stage kt=0 into buffer 0 --------------------------------
    {
        f32x4 f = __builtin_nontemporal_load(agp);  // A(0): issue FIRST
        __builtin_amdgcn_sched_barrier(0);
        const char* g = bg;
        char* l0 = sB0v + bl_off;
#pragma unroll
        for (int j = 0; j < 8; ++j)
            glds16(g + (j * 64 + lane) * 16, l0 + (j * 64 + lane) * 16);
        __builtin_amdgcn_sched_barrier(0);
        union { _Float16 hh[4]; uint2 u; } pk;      // use of f -> vmcnt(8)
        pk.hh[0] = (_Float16)f.x; pk.hh[1] = (_Float16)f.y;
        pk.hh[2] = (_Float16)f.z; pk.hh[3] = (_Float16)f.w;
        *(uint2*)(sA0v + awoff) = pk.u;
        asm volatile("s_waitcnt lgkmcnt(0)" ::: "memory");
        __builtin_amdgcn_s_barrier();
        __builtin_amdgcn_sched_barrier(0);
    }

    // One k-step. AB/BB: current read buffers. AN/BN: buffers being staged.
    // HAVE_NEXT is wave-uniform.
#define KSTEP(KT_I, AB, BB, AN, BN, HAVE_NEXT)                                    \
    {                                                                             \
        f32x4 f;                                                                  \
        if (HAVE_NEXT) {                                                          \
            f = __builtin_nontemporal_load(agp + ((KT_I) + 1) * 8);               \
            __builtin_amdgcn_sched_barrier(0);                                    \
            const char* g = bg + (size_t)((KT_I) + 1) * 8192;                     \
            char* l0 = (BN) + bl_off;                                             \
            _Pragma("unroll")                                                     \
            for (int j = 0; j < 8; ++j)                                           \
                glds16(g + (j * 64 + lane) * 16, l0 + (j * 64 + lane) * 16);      \
            __builtin_amdgcn_sched_barrier(0);                                    \
            /* 17 outstanding: 8x B(t) oldest + A(t+1) + 8x B(t+1).         */    \
            /* vmcnt(9): in-order retire -> exactly the 8 B(t) are done.    */    \
            asm volatile("s_waitcnt vmcnt(9)" ::: "memory");                      \
        } else {                                                                  \
            asm volatile("s_waitcnt vmcnt(0)" ::: "memory");                      \
        }                                                                         \
        half8 af[4];                                                              \
        _Pragma("unroll")                                                         \
        for (int i = 0; i < 4; ++i)                                               \
            af[i] = *(const half8*)((AB) + ardoff + i * 256);                     \
        _Pragma("unroll")                                                         \
        for (int j = 0; j < 8; ++j) {                                             \
            half8 bf = *(const half8*)((BB) + brdoff + j * 256);                  \
            _Pragma("unroll")                                                     \
            for (int i = 0; i < 4; ++i)                                           \
                acc[i][j] =                                                       \
                    __builtin_amdgcn_mfma_f32_16x16x32_f16(af[i], bf, acc[i][j],  \
                                                           0, 0, 0);              \
        }                                                                         \
        __builtin_amdgcn_sched_barrier(0);                                        \
        if (HAVE_NEXT) {                                                          \
            union { _Float16 hh[4]; uint2 u; } pk;  /* use of f -> vmcnt(8) */    \
            pk.hh[0] = (_Float16)f.x; pk.hh[1] = (_Float16)f.y;                   \
            pk.hh[2] = (_Float16)f.z; pk.hh[3] = (_Float16)f.w;                   \
            *(uint2*)((AN) + awoff) = pk.u;                                       \
        }                                                                         \
        asm volatile("s_waitcnt lgkmcnt(0)" ::: "memory");                        \
        __builtin_amdgcn_s_barrier();                                             \
        __builtin_amdgcn_sched_barrier(0);                                        \
    }

#pragma clang loop unroll(disable)
    for (int kt2 = 0; kt2 < KT; kt2 += 2) {
        KSTEP(kt2, sA0v, sB0v, sA1v, sB1v, true);
        KSTEP(kt2 + 1, sA1v, sB1v, sA0v, sB0v, (kt2 + 2 < KT));
    }
#undef KSTEP

    // ---- epilogue: tanh(acc + hproj)*v, reduce over all 1024 cols ----------
    // C layout: col = fm, row(frag) = fg*4 + r.  acc[i][j] covers rows i*16+..,
    // cols (wv*128 + j*16 + ..).
    float sums[4][4];
#pragma unroll
    for (int i = 0; i < 4; ++i)
#pragma unroll
        for (int r = 0; r < 4; ++r) sums[i][r] = 0.0f;

#pragma unroll
    for (int j = 0; j < 8; ++j) {
        int h = wv * 128 + j * 16 + fm;
        float vv = v[h];
#pragma unroll
        for (int i = 0; i < 4; ++i) {
#pragma unroll
            for (int r = 0; r < 4; ++r) {
                int row = i * 16 + fg * 4 + r;     // 0..63 within slab
                int b = row & 31;                  // r0 % 32 == 0
                float x = acc[i][j][r] + hp[b * HID + h];
                float e2 = __expf(2.0f * x);
                float th = 1.0f - 2.0f / (e2 + 1.0f);
                sums[i][r] += th * vv;
            }
        }
    }
#pragma unroll
    for (int i = 0; i < 4; ++i)
#pragma unroll
        for (int r = 0; r < 4; ++r) {
            float s = sums[i][r];
            s += __shfl_xor(s, 1);
            s += __shfl_xor(s, 2);
            s += __shfl_xor(s, 4);
            s += __shfl_xor(s, 8);
            sums[i][r] = s;
        }
    __syncthreads();                    // done with frag LDS; reuse as reduction
    float* red = (float*)sB0v;
    if (fm == 0) {
#pragma unroll
        for (int i = 0; i < 4; ++i)
#pragma unroll
            for (int r = 0; r < 4; ++r)
                red[wv * 64 + i * 16 + fg * 4 + r] = sums[i][r];
    }
    __syncthreads();
    if (tid < 64) {
        float tot = 0.0f;
#pragma unroll
        for (int w = 0; w < 8; ++w) tot += red[w * 64 + tid];
        score[r0 + tid] = tot;          // row m = s*32 + b
    }
}

// ---------------------------------------------------------------------------
// Softmax over s per batch b.
// ---------------------------------------------------------------------------
__global__ __launch_bounds__(256) void softmax_kernel(const float* __restrict__ score,
                                                      float* __restrict__ out) {
    int b = blockIdx.x;
    int tid = threadIdx.x;
    __shared__ float redm[4];
    __shared__ float reds[4];
    float vals[8];
    float mx = -1e30f;
#pragma unroll
    for (int k = 0; k < 8; ++k) {
        int s = k * 256 + tid;
        float a = score[(size_t)s * 32 + b];
        vals[k] = a;
        mx = fmaxf(mx, a);
    }
    for (int d = 1; d < 64; d <<= 1) mx = fmaxf(mx, __shfl_xor(mx, d));
    int wv = tid >> 6;
    if ((tid & 63) == 0) redm[wv] = mx;
    __syncthreads();
    mx = fmaxf(fmaxf(redm[0], redm[1]), fmaxf(redm[2], redm[3]));
    float sum = 0.0f;
#pragma unroll
    for (int k = 0; k < 8; ++k) {
        vals[k] = __expf(vals[k] - mx);
        sum += vals[k];
    }
    for (int d = 1; d < 64; d <<= 1) sum += __shfl_xor(sum, d);
    if ((tid & 63) == 0) reds[wv] = sum;
    __syncthreads();
    sum = reds[0] + reds[1] + reds[2] + reds[3];
    float inv = 1.0f / sum;
#pragma unroll
    for (int k = 0; k < 8; ++k) out[b * SEQ + k * 256 + tid] = vals[k] * inv;
}

// ---------------------------------------------------------------------------
extern "C" void kernel_launch(void* const* d_in, const int* in_sizes, int n_in,
                              void* d_out, int out_size, void* d_ws, size_t ws_size,
                              hipStream_t stream) {
    const float* hidden = (const float*)d_in[0];
    const float* enc    = (const float*)d_in[1];
    const float* W      = (const float*)d_in[2];
    const float* bias   = (const float*)d_in[3];
    const float* v      = (const float*)d_in[4];
    float* out = (float*)d_out;

    char* ws = (char*)d_ws;
    _Float16* packB = (_Float16*)ws;                              // 4 MiB
    float* hp       = (float*)(ws + (4u << 20));                  // 128 KiB
    float* score    = (float*)(ws + (4u << 20) + (128u << 10));   // 256 KiB

    pack_b_kernel<<<1024, 256, 0, stream>>>(W, packB);
    hproj_kernel<<<dim3(32, 16), 256, 0, stream>>>(hidden, W, bias, hp);
    attn_gemm_kernel<<<MTOT / 64, 512, 0, stream>>>(enc, packB, hp, v, score);
    softmax_kernel<<<BAT, 256, 0, stream>>>(score, out);
}

// Round 2
// 991.504 us; speedup vs baseline: 1.0756x; 1.0255x over previous
//
#include <hip/hip_runtime.h>
#include <hip/hip_fp16.h>

// S=2048, B=32, H=1024.
// out[b][s] = softmax_s( sum_h tanh( (enc[s][b] @ We)[h] + hproj[b][h] ) * v[h] )
//
// GEMM: M = 65536 rows (K-contiguous), K = 2048, N = 1024.
// R2 RESTRUCTURE: B cache traffic = (M/M_block)*4MB was the bottleneck
// (4 GB from L3 at ~10 TB/s == 462 us). Now each block owns a 128-row
// M-slab and HALF of N (512 cols): B traffic halves to 2 GB. Wave =
// 128 rows x 64 cols, acc[8][4] (same 128 acc regs, same 32 MFMA/kt).
// The two col-halves of an M-slab are pinned to opposite XCD groups at
// the same dispatch slot so the A slab is fetched from HBM once and hits
// L3 for the twin; each XCD's L2 only holds its 2 MB half of packB.
// Scores are written as two partial planes, summed in the softmax kernel.
//
// Pipeline (per wave, per kt): [issue 2 A(t+1) f32x4 loads] [issue 4 glds
// B(t+1)] [vmcnt(6): own B(t) done] [ds_read frags + 32 MFMA] [vmcnt(4)
// auto: A(t+1) regs ready; cvt+ds_write] [lgkmcnt(0); s_barrier].
// B is staged per-wave and read only by that wave -> counted per-wave
// vmcnt, no cross-wave B hazard. Only A (8 KB tile) is cross-wave.

typedef _Float16 half8 __attribute__((ext_vector_type(8)));
typedef float floatx4 __attribute__((ext_vector_type(4)));
typedef float f32x4 __attribute__((ext_vector_type(4)));

constexpr int SEQ = 2048;
constexpr int BAT = 32;
constexpr int HID = 1024;
constexpr int KDIM = 2048;
constexpr int MTOT = SEQ * BAT;   // 65536
constexpr int KT = 64;            // K tiles of 32

constexpr int B_BUF = 32768;          // 8 waves * 256 chunks * 16B (32k x 512c fp16)
constexpr int A_PITCH = 128 * 16 + 16; // 2064 B per k-octet group (pad breaks bank alias)
constexpr int A_BUF = 4 * A_PITCH;    // 8256

__device__ __forceinline__ void glds16(const void* g, void* l) {
    __builtin_amdgcn_global_load_lds((__attribute__((address_space(1))) void*)(g),
                                     (__attribute__((address_space(3))) void*)(l), 16, 0, 0);
}

// ---------------------------------------------------------------------------
// Pack We into fp16 chunks: packB[(((nt2*64+kt)*4 + g)*64 + n)*8 + j]
//   = We[kt*32 + g*8 + j][nt2*64 + n]     (nt2: 16 groups of 64 cols)
// Per (nt2,kt): 4 KB contiguous.
// ---------------------------------------------------------------------------
__global__ __launch_bounds__(256) void pack_b_kernel(const float* __restrict__ W,
                                                     _Float16* __restrict__ pb) {
    int t = blockIdx.x * blockDim.x + threadIdx.x;   // 0..262143
    int nt2 = t >> 14;         // 0..15
    int rem = t & 16383;
    int kt = rem >> 8;         // 0..63
    int c = rem & 255;
    int g = c >> 6;            // 0..3
    int n = c & 63;
    int h = nt2 * 64 + n;
    int e0 = kt * 32 + g * 8;
    const float* src = W + (size_t)(1024 + e0) * 1024 + h;
    union { _Float16 hh[8]; uint4 u; } tmp;
#pragma unroll
    for (int j = 0; j < 8; ++j) tmp.hh[j] = (_Float16)src[(size_t)j * 1024];
    *(uint4*)(pb + (size_t)t * 8) = tmp.u;
}

// ---------------------------------------------------------------------------
// hproj[b][h] = hidden[b] . W[:,h] + bias[h]. 4-way K-split, 512 blocks.
// ---------------------------------------------------------------------------
__global__ __launch_bounds__(256) void hproj_kernel(const float* __restrict__ hidden,
                                                    const float* __restrict__ W,
                                                    const float* __restrict__ bias,
                                                    float* __restrict__ hp) {
    int b = blockIdx.x;                 // 0..31
    int h0 = blockIdx.y * 64;           // 16 y-blocks
    int hl = threadIdx.x & 63;
    int ks = threadIdx.x >> 6;          // 0..3
    const float* hr = hidden + b * HID + ks * 256;
    const float* wc = W + (size_t)(ks * 256) * HID + h0 + hl;
    float acc = 0.0f;
#pragma unroll 8
    for (int e = 0; e < 256; ++e) acc += hr[e] * wc[(size_t)e * HID];
    __shared__ float red[256];
    red[threadIdx.x] = acc;
    __syncthreads();
    if (threadIdx.x < 64)
        hp[b * HID + h0 + threadIdx.x] = red[threadIdx.x] + red[64 + threadIdx.x] +
                                         red[128 + threadIdx.x] + red[192 + threadIdx.x] +
                                         bias[h0 + threadIdx.x];
}

// ---------------------------------------------------------------------------
// Main fused kernel. Grid 1024: block -> (mt 0..511, ch 0..1) via XCD pin:
// XCDs 0-3 take ch=0, XCDs 4-7 take ch=1; same mt pairs are co-scheduled.
// ---------------------------------------------------------------------------
__global__ __launch_bounds__(512, 2) void attn_gemm_kernel(
    const float* __restrict__ enc, const _Float16* __restrict__ pb,
    const float* __restrict__ hp, const float* __restrict__ v,
    float* __restrict__ score) {
    __shared__ char sB0v[B_BUF];
    __shared__ char sB1v[B_BUF];
    __shared__ char sA0v[A_BUF];
    __shared__ char sA1v[A_BUF];

    const int tid = threadIdx.x;
    const int lane = tid & 63;
    const int wv = tid >> 6;            // 0..7
    const int bx = blockIdx.x;          // 0..1023
    const int q = bx & 7;               // assumed XCD id (perf-only if wrong)
    const int ch = q >> 2;              // col-half 0/1
    const int mt = (bx >> 3) * 4 + (q & 3);   // 0..511
    const size_t r0 = (size_t)mt * 128;
    const int fm = lane & 15;
    const int fg = lane >> 4;
    const int nt2 = ch * 8 + wv;        // 64-col group id 0..15

    // B staging: wave wv stages its own 64-col slice. 4 glds16/thread/kt.
    const char* bg = (const char*)pb + (size_t)nt2 * KT * 4096;
    const int bl_off = wv * 4096;

    // A staging: thread loads two f32x4 of the 128x32 f32 tile per kt.
    const int arow0 = tid >> 3;         // 0..63
    const int arow1 = arow0 + 64;       // 64..127
    const int ac4 = tid & 7;            // f32x4 col
    const f32x4* agp0 = (const f32x4*)(enc + (r0 + arow0) * KDIM) + ac4;
    const f32x4* agp1 = (const f32x4*)(enc + (r0 + arow1) * KDIM) + ac4;
    const int g4 = ac4 >> 1, sub = ac4 & 1;
    const int awoff0 = g4 * A_PITCH + arow0 * 16 + sub * 8;
    const int awoff1 = g4 * A_PITCH + arow1 * 16 + sub * 8;

    // Fragment read offsets.
    const int ardoff = fg * A_PITCH + fm * 16;                // + i*256
    const int brdoff = wv * 4096 + fg * 1024 + fm * 16;       // + j*256

    floatx4 acc[8][4];
#pragma unroll
    for (int i = 0; i < 8; ++i)
#pragma unroll
        for (int j = 0; j < 4; ++j) acc[i][j] = (floatx4)0.0f;

    // ---- prologue: stage kt=0 into buffer 0 --------------------------------
    {
        f32x4 f0 = __builtin_nontemporal_load(agp0);
        f32x4 f1 = __builtin_nontemporal_load(agp1);
        __builtin_amdgcn_sched_barrier(0);
        const char* g = bg;
        char* l0 = sB0v + bl_off;
#pragma unroll
        for (int j = 0; j < 4; ++j)
            glds16(g + (j * 64 + lane) * 16, l0 + (j * 64 + lane) * 16);
        __builtin_amdgcn_sched_barrier(0);
        union { _Float16 hh[4]; uint2 u; } pk0, pk1;
        pk0.hh[0] = (_Float16)f0.x; pk0.hh[1] = (_Float16)f0.y;
        pk0.hh[2] = (_Float16)f0.z; pk0.hh[3] = (_Float16)f0.w;
        *(uint2*)(sA0v + awoff0) = pk0.u;
        pk1.hh[0] = (_Float16)f1.x; pk1.hh[1] = (_Float16)f1.y;
        pk1.hh[2] = (_Float16)f1.z; pk1.hh[3] = (_Float16)f1.w;
        *(uint2*)(sA0v + awoff1) = pk1.u;
        asm volatile("s_waitcnt lgkmcnt(0)" ::: "memory");
        __builtin_amdgcn_s_barrier();
        __builtin_amdgcn_sched_barrier(0);
    }

    // One k-step. AB/BB: current read buffers. AN/BN: buffers being staged.
#define KSTEP(KT_I, AB, BB, AN, BN, HAVE_NEXT)                                    \
    {                                                                             \
        f32x4 f0, f1;                                                             \
        if (HAVE_NEXT) {                                                          \
            f0 = __builtin_nontemporal_load(agp0 + ((KT_I) + 1) * 8);             \
            f1 = __builtin_nontemporal_load(agp1 + ((KT_I) + 1) * 8);             \
            __builtin_amdgcn_sched_barrier(0);                                    \
            const char* g = bg + (size_t)((KT_I) + 1) * 4096;                     \
            char* l0 = (BN) + bl_off;                                             \
            _Pragma("unroll")                                                     \
            for (int j = 0; j < 4; ++j)                                           \
                glds16(g + (j * 64 + lane) * 16, l0 + (j * 64 + lane) * 16);      \
            __builtin_amdgcn_sched_barrier(0);                                    \
            /* outstanding: 4x B(t) oldest + 2x A(t+1) + 4x B(t+1) = 10.   */     \
            /* vmcnt(6): in-order retire -> the 4 B(t) are done.           */     \
            asm volatile("s_waitcnt vmcnt(6)" ::: "memory");                      \
        } else {                                                                  \
            asm volatile("s_waitcnt vmcnt(0)" ::: "memory");                      \
        }                                                                         \
        half8 af[8];                                                              \
        _Pragma("unroll")                                                         \
        for (int i = 0; i < 8; ++i)                                               \
            af[i] = *(const half8*)((AB) + ardoff + i * 256);                     \
        _Pragma("unroll")                                                         \
        for (int j = 0; j < 4; ++j) {                                             \
            half8 bf = *(const half8*)((BB) + brdoff + j * 256);                  \
            _Pragma("unroll")                                                     \
            for (int i = 0; i < 8; ++i)                                           \
                acc[i][j] =                                                       \
                    __builtin_amdgcn_mfma_f32_16x16x32_f16(af[i], bf, acc[i][j],  \
                                                           0, 0, 0);              \
        }                                                                         \
        __builtin_amdgcn_sched_barrier(0);                                        \
        if (HAVE_NEXT) {                                                          \
            union { _Float16 hh[4]; uint2 u; } pk0, pk1;                          \
            pk0.hh[0] = (_Float16)f0.x; pk0.hh[1] = (_Float16)f0.y;               \
            pk0.hh[2] = (_Float16)f0.z; pk0.hh[3] = (_Float16)f0.w;               \
            *(uint2*)((AN) + awoff0) = pk0.u;                                     \
            pk1.hh[0] = (_Float16)f1.x; pk1.hh[1] = (_Float16)f1.y;               \
            pk1.hh[2] = (_Float16)f1.z; pk1.hh[3] = (_Float16)f1.w;               \
            *(uint2*)((AN) + awoff1) = pk1.u;                                     \
        }                                                                         \
        asm volatile("s_waitcnt lgkmcnt(0)" ::: "memory");                        \
        __builtin_amdgcn_s_barrier();                                             \
        __builtin_amdgcn_sched_barrier(0);                                        \
    }

#pragma clang loop unroll(disable)
    for (int kt2 = 0; kt2 < KT; kt2 += 2) {
        KSTEP(kt2, sA0v, sB0v, sA1v, sB1v, true);
        KSTEP(kt2 + 1, sA1v, sB1v, sA0v, sB0v, (kt2 + 2 < KT));
    }
#undef KSTEP

    // ---- epilogue: tanh(acc + hproj)*v, reduce over this block's 512 cols --
    // C layout: col = fm, row(frag) = fg*4 + r.  acc[i][j] covers rows i*16+..,
    // cols (ch*512 + wv*64 + j*16 + ..).
    float sums[8][4];
#pragma unroll
    for (int i = 0; i < 8; ++i)
#pragma unroll
        for (int r = 0; r < 4; ++r) sums[i][r] = 0.0f;

#pragma unroll
    for (int j = 0; j < 4; ++j) {
        int h = ch * 512 + wv * 64 + j * 16 + fm;
        float vv = v[h];
#pragma unroll
        for (int i = 0; i < 8; ++i) {
#pragma unroll
            for (int r = 0; r < 4; ++r) {
                int row = i * 16 + fg * 4 + r;     // 0..127 within slab
                int b = row & 31;                  // r0 % 128 == 0
                float x = acc[i][j][r] + hp[b * HID + h];
                float e2 = __expf(2.0f * x);
                float th = 1.0f - 2.0f / (e2 + 1.0f);
                sums[i][r] += th * vv;
            }
        }
    }
#pragma unroll
    for (int i = 0; i < 8; ++i)
#pragma unroll
        for (int r = 0; r < 4; ++r) {
            float s = sums[i][r];
            s += __shfl_xor(s, 1);
            s += __shfl_xor(s, 2);
            s += __shfl_xor(s, 4);
            s += __shfl_xor(s, 8);
            sums[i][r] = s;
        }
    __syncthreads();                    // done with frag LDS; reuse as reduction
    float* red = (float*)sB0v;          // 8 waves * 128 rows
    if (fm == 0) {
#pragma unroll
        for (int i = 0; i < 8; ++i)
#pragma unroll
            for (int r = 0; r < 4; ++r)
                red[wv * 128 + i * 16 + fg * 4 + r] = sums[i][r];
    }
    __syncthreads();
    if (tid < 128) {
        float tot = 0.0f;
#pragma unroll
        for (int w = 0; w < 8; ++w) tot += red[w * 128 + tid];
        score[(size_t)ch * MTOT + r0 + tid] = tot;   // partial plane ch
    }
}

// ---------------------------------------------------------------------------
// Softmax over s per batch b. Sums the two partial score planes.
// ---------------------------------------------------------------------------
__global__ __launch_bounds__(256) void softmax_kernel(const float* __restrict__ score,
                                                      float* __restrict__ out) {
    int b = blockIdx.x;
    int tid = threadIdx.x;
    __shared__ float redm[4];
    __shared__ float reds[4];
    float vals[8];
    float mx = -1e30f;
#pragma unroll
    for (int k = 0; k < 8; ++k) {
        int s = k * 256 + tid;
        float a = score[(size_t)s * 32 + b] + score[(size_t)MTOT + (size_t)s * 32 + b];
        vals[k] = a;
        mx = fmaxf(mx, a);
    }
    for (int d = 1; d < 64; d <<= 1) mx = fmaxf(mx, __shfl_xor(mx, d));
    int wv = tid >> 6;
    if ((tid & 63) == 0) redm[wv] = mx;
    __syncthreads();
    mx = fmaxf(fmaxf(redm[0], redm[1]), fmaxf(redm[2], redm[3]));
    float sum = 0.0f;
#pragma unroll
    for (int k = 0; k < 8; ++k) {
        vals[k] = __expf(vals[k] - mx);
        sum += vals[k];
    }
    for (int d = 1; d < 64; d <<= 1) sum += __shfl_xor(sum, d);
    if ((tid & 63) == 0) reds[wv] = sum;
    __syncthreads();
    sum = reds[0] + reds[1] + reds[2] + reds[3];
    float inv = 1.0f / sum;
#pragma unroll
    for (int k = 0; k < 8; ++k) out[b * SEQ + k * 256 + tid] = vals[k] * inv;
}

// ---------------------------------------------------------------------------
extern "C" void kernel_launch(void* const* d_in, const int* in_sizes, int n_in,
                              void* d_out, int out_size, void* d_ws, size_t ws_size,
                              hipStream_t stream) {
    const float* hidden = (const float*)d_in[0];
    const float* enc    = (const float*)d_in[1];
    const float* W      = (const float*)d_in[2];
    const float* bias   = (const float*)d_in[3];
    const float* v      = (const float*)d_in[4];
    float* out = (float*)d_out;

    char* ws = (char*)d_ws;
    _Float16* packB = (_Float16*)ws;                              // 4 MiB
    float* hp       = (float*)(ws + (4u << 20));                  // 128 KiB
    float* score    = (float*)(ws + (4u << 20) + (128u << 10));   // 512 KiB (2 planes)

    pack_b_kernel<<<1024, 256, 0, stream>>>(W, packB);
    hproj_kernel<<<dim3(32, 16), 256, 0, stream>>>(hidden, W, bias, hp);
    attn_gemm_kernel<<<1024, 512, 0, stream>>>(enc, packB, hp, v, score);
    softmax_kernel<<<BAT, 256, 0, stream>>>(score, out);
}